// Round 12
// baseline (86.885 us; speedup 1.0000x reference)
//
#include <hip/hip_runtime.h>
#include <hip/hip_bf16.h>
#include <stdint.h>

#define NB    4096
#define NROWS 8192
#define DIM   512
#define BM    128
#define TK    128                     // K per MX-fp8 MFMA tile
#define NKT   4                       // K-tiles per output tile
#define SBLK  1024                    // simexp grid: 4 blocks/CU, persistent

typedef __attribute__((ext_vector_type(4))) float f32x4;
typedef __attribute__((ext_vector_type(4))) int   i32x4;
typedef __attribute__((ext_vector_type(8))) int   i32x8;

#define SCALE_E8M0 0x7B7B7B7Bu   // 2^-4 per 32-elem block, all blocks

// f32 -> OCP e4m3fn, RNE. Inputs |x| <= ~8 here (no sat needed).
__device__ __forceinline__ unsigned char f2e4m3(float x) {
  uint32_t u = __float_as_uint(x);
  uint32_t s = (u >> 24) & 0x80u;
  uint32_t e = (u >> 23) & 0xffu;
  if (e < 117u) return (unsigned char)s;          // < 2^-10 -> 0
  if (e >= 121u) {                                // normal fp8 range
    u += 0x7FFFFu + ((u >> 20) & 1u);             // RNE on mantissa bit 20
    e = (u >> 23) & 0xffu;
    uint32_t m = (u >> 20) & 7u;
    return (unsigned char)(s | ((e - 120u) << 3) | m);
  }
  float af = __uint_as_float(u & 0x7fffffffu);    // subnormal: step 2^-9
  int q = (int)(af * 512.0f + 0.5f);
  return (unsigned char)(q > 7 ? (s | 0x08u) : (s | (uint32_t)q));
}

__device__ __forceinline__ void gload_lds16(const void* g, void* l) {
  __builtin_amdgcn_global_load_lds(
      (const __attribute__((address_space(1))) void*)g,
      (__attribute__((address_space(3))) void*)l, 16, 0, 0);
}

__device__ __forceinline__ i32x8 ld_frag(const char* base, int o0, int o1) {
  i32x4 lo = *(const i32x4*)(base + o0);
  i32x4 hi = *(const i32x4*)(base + o1);
  i32x8 r = {lo[0], lo[1], lo[2], lo[3], hi[0], hi[1], hi[2], hi[3]};
  return r;
}

// ---- Kernel 1: normalize -> fp8 P (v*16), pos partials; 512 blocks x2 -----
__global__ __launch_bounds__(256) void normalize_pos_kernel(
    const float* __restrict__ zi, const float* __restrict__ zj,
    unsigned char* __restrict__ p, float* __restrict__ rowsum,
    float* __restrict__ posp) {
  __shared__ float ws4[4];
  const int wave = threadIdx.x >> 6;
  const int lane = threadIdx.x & 63;

  int gt = blockIdx.x * 256 + threadIdx.x;
  if (gt < NROWS) rowsum[gt] = 0.f;

  float dtot = 0.f;
#pragma unroll
  for (int it = 0; it < 2; ++it) {
    const int i = blockIdx.x * 4 + wave + it * 2048;   // 0..4095
    const float4* sa = (const float4*)(zi + (size_t)i * DIM);
    const float4* sb = (const float4*)(zj + (size_t)i * DIM);
    float4 a0 = sa[lane * 2], a1 = sa[lane * 2 + 1];
    float4 b0 = sb[lane * 2], b1 = sb[lane * 2 + 1];
    float va[8] = {a0.x, a0.y, a0.z, a0.w, a1.x, a1.y, a1.z, a1.w};
    float vb[8] = {b0.x, b0.y, b0.z, b0.w, b1.x, b1.y, b1.z, b1.w};
    float ssa = 0.f, ssb = 0.f;
#pragma unroll
    for (int j = 0; j < 8; ++j) { ssa += va[j] * va[j]; ssb += vb[j] * vb[j]; }
#pragma unroll
    for (int off = 32; off; off >>= 1) {
      ssa += __shfl_xor(ssa, off);
      ssb += __shfl_xor(ssb, off);
    }
    float inva = rsqrtf(ssa), invb = rsqrtf(ssb);
    union { unsigned char b[8]; uint2 v; } qa, qb;
#pragma unroll
    for (int j = 0; j < 8; ++j) {
      float na = va[j] * inva, nb = vb[j] * invb;
      qa.b[j] = f2e4m3(na * 16.0f);
      qb.b[j] = f2e4m3(nb * 16.0f);
      dtot += na * nb;
    }
    *(uint2*)(p + (size_t)i * DIM + lane * 8)        = qa.v;
    *(uint2*)(p + (size_t)(i + NB) * DIM + lane * 8) = qb.v;
  }

#pragma unroll
  for (int off = 32; off; off >>= 1) dtot += __shfl_xor(dtot, off);
  if (lane == 0) ws4[wave] = dtot;
  __syncthreads();
  if (threadIdx.x == 0)
    posp[blockIdx.x] = 4.0f * (ws4[0] + ws4[1] + ws4[2] + ws4[3]);
}

// decode (xcd x, local slot l) -> tile (bi,bj); supertile partition (R3/R6):
__device__ __forceinline__ void decode_tile(int x, int l, int* pbi, int* pbj) {
  if (x < 6) {
    const int sqi[6] = {0, 0, 0, 1, 1, 2};
    const int sqj[6] = {1, 2, 3, 2, 3, 3};
    *pbi = sqi[x] * 16 + (l >> 4);
    *pbj = sqj[x] * 16 + (l & 15);
  } else {
    int s  = (x == 6) ? 0 : 2;
    int ll = l;
    if (ll >= 136) { ll -= 136; s += 1; }
    int i = 0;
    while ((i + 1) * (33 - (i + 1)) / 2 <= ll) ++i;
    int j = i + (ll - i * (33 - i) / 2);
    *pbi = s * 16 + i;
    *pbj = s * 16 + j;
  }
}

// ---- Kernel 2: symmetric fused S = 2*P*P^T (MX-fp8) -> exp -> row+col sums
// 1024 persistent blocks, 4/CU (32 KB LDS single buffer, VGPR<=128).
// Per-CU latency hiding comes from 4 independent phase-streams (m114-style
// co-scheduling) — the session-measured lever (R1 vs R11). Phase = R8's
// proven drain loop. Block b serves XCD b&7 with 2-3 consecutive supertile
// tiles (shared bi -> A-panel L2 reuse).
__global__ __launch_bounds__(256, 4) void simexp_kernel(
    const unsigned char* __restrict__ p, float* __restrict__ rowsum) {
  __shared__ __align__(16) unsigned char As[BM * TK];   // 16 KB
  __shared__ __align__(16) unsigned char Bs[BM * TK];   // 16 KB

  const int x  = blockIdx.x & 7;         // XCD
  const int lb = blockIdx.x >> 3;        // 0..127 local block
  int start, cnt;
  if (x < 6)        { start = lb * 2; cnt = 2; }                 // 256 tiles
  else if (lb < 112){ start = lb * 2; cnt = 2; }                 // 272 tiles
  else              { start = 224 + (lb - 112) * 3; cnt = 3; }

  const int tid  = threadIdx.x;
  const int wave = tid >> 6;
  const int lane = tid & 63;
  const int wm   = wave >> 1;
  const int wn   = wave & 1;
  const int frow = lane & 15;
  const int kc   = lane >> 4;            // 0..3 : 32-elem k-block

  const int row8 = lane >> 3;            // 0..7
  const int gch  = (lane & 7) ^ row8;    // pre-swizzled 16B chunk

#define STAGE(bi_, bj_, t_)                                                   \
  {                                                                           \
    const unsigned char* pa_ = p + (size_t)((bi_)*BM) * DIM;                  \
    const unsigned char* pb_ = p + (size_t)((bj_)*BM) * DIM;                  \
    _Pragma("unroll")                                                         \
    for (int q = 0; q < 4; ++q) {                                             \
      int rbase = q * 32 + wave * 8;                                          \
      gload_lds16(pa_ + (size_t)(rbase + row8) * DIM + (t_)*TK + gch * 16,    \
                  (char*)As + rbase * 128);                                   \
      gload_lds16(pb_ + (size_t)(rbase + row8) * DIM + (t_)*TK + gch * 16,    \
                  (char*)Bs + rbase * 128);                                   \
    }                                                                         \
  }

  // ds_read byte offsets (verified R8): row*128 + ((kc*2+j)^(row&7))*16
  int offA[4][2], offB[4][2];
#pragma unroll
  for (int m = 0; m < 4; ++m) {
    int row = wm * 64 + m * 16 + frow;
#pragma unroll
    for (int j = 0; j < 2; ++j)
      offA[m][j] = row * 128 + ((kc * 2 + j) ^ (row & 7)) * 16;
  }
#pragma unroll
  for (int n = 0; n < 4; ++n) {
    int row = wn * 64 + n * 16 + frow;
#pragma unroll
    for (int j = 0; j < 2; ++j)
      offB[n][j] = row * 128 + ((kc * 2 + j) ^ (row & 7)) * 16;
  }

  const int r4 = lane >> 4;   // C/D: col = lane&15, row = (lane>>4)*4 + reg
  const int cl = lane & 15;

  for (int tt = 0; tt < cnt; ++tt) {
    int cbi, cbj;
    decode_tile(x, start + tt, &cbi, &cbj);
    const bool diag = (cbi == cbj);

    f32x4 acc[4][4] = {};

#pragma unroll
    for (int t = 0; t < NKT; ++t) {
      STAGE(cbi, cbj, t);
      __syncthreads();                       // drain + all waves' tile in
      {
        i32x8 af[4], bfr[4];
#pragma unroll
        for (int m = 0; m < 4; ++m)
          af[m] = ld_frag((const char*)As, offA[m][0], offA[m][1]);
#pragma unroll
        for (int n = 0; n < 4; ++n)
          bfr[n] = ld_frag((const char*)Bs, offB[n][0], offB[n][1]);
#pragma unroll
        for (int m = 0; m < 4; ++m)
#pragma unroll
          for (int n = 0; n < 4; ++n)
            acc[m][n] = __builtin_amdgcn_mfma_scale_f32_16x16x128_f8f6f4(
                af[m], bfr[n], acc[m][n], 0, 0, 0, SCALE_E8M0, 0, SCALE_E8M0);
      }
      __syncthreads();                       // reads done -> safe overwrite
    }

    // ---- epilogue for tile (cbi,cbj) (R8-verified) ----
    float rowpart[4][4];
    float colpart[4] = {0.f, 0.f, 0.f, 0.f};

    if (diag) {
#pragma unroll
      for (int m = 0; m < 4; ++m)
#pragma unroll
        for (int r = 0; r < 4; ++r) {
          int grow = cbi * BM + wm * 64 + m * 16 + r4 * 4 + r;
          float s = 0.f;
#pragma unroll
          for (int n = 0; n < 4; ++n) {
            int gcol = cbj * BM + wn * 64 + n * 16 + cl;
            float e  = __expf(2.0f * acc[m][n][r]);
            s += (grow == gcol) ? 0.f : e;
          }
          rowpart[m][r] = s;
        }
    } else {
#pragma unroll
      for (int m = 0; m < 4; ++m)
#pragma unroll
        for (int r = 0; r < 4; ++r) {
          float s = 0.f;
#pragma unroll
          for (int n = 0; n < 4; ++n) {
            float e = __expf(2.0f * acc[m][n][r]);
            s += e;
            colpart[n] += e;
          }
          rowpart[m][r] = s;
        }
    }

#pragma unroll
    for (int m = 0; m < 4; ++m)
#pragma unroll
      for (int r = 0; r < 4; ++r) {
        float s = rowpart[m][r];
        s += __shfl_xor(s, 1);
        s += __shfl_xor(s, 2);
        s += __shfl_xor(s, 4);
        s += __shfl_xor(s, 8);
        if (cl == 0) {
          int grow = cbi * BM + wm * 64 + m * 16 + r4 * 4 + r;
          atomicAdd(&rowsum[grow], s);
        }
      }

    if (!diag) {
#pragma unroll
      for (int n = 0; n < 4; ++n) {
        float c = colpart[n];
        c += __shfl_xor(c, 16);
        c += __shfl_xor(c, 32);
        if (r4 == 0) {
          int gcol = cbj * BM + wn * 64 + n * 16 + cl;
          atomicAdd(&rowsum[gcol], c);
        }
      }
    }
  }
}

// ---- Kernel 3: finalize loss ---------------------------------------------
__global__ __launch_bounds__(256) void finalize_kernel(
    const float* __restrict__ rowsum, const float* __restrict__ posp,
    float* __restrict__ out) {
  __shared__ float ws4[4];
  int tid = threadIdx.x;
  float v = 0.f;
  for (int i = tid; i < NROWS; i += 256) v += logf(rowsum[i]);
  for (int i = tid; i < 512; i += 256) v -= posp[i];
#pragma unroll
  for (int off = 32; off; off >>= 1) v += __shfl_xor(v, off);
  if ((tid & 63) == 0) ws4[tid >> 6] = v;
  __syncthreads();
  if (tid == 0)
    out[0] = (ws4[0] + ws4[1] + ws4[2] + ws4[3]) / (float)NROWS;
}

extern "C" void kernel_launch(void* const* d_in, const int* in_sizes, int n_in,
                              void* d_out, int out_size, void* d_ws,
                              size_t ws_size, hipStream_t stream) {
  const float* zi = (const float*)d_in[0];
  const float* zj = (const float*)d_in[1];
  float* out      = (float*)d_out;

  char* ws          = (char*)d_ws;
  unsigned char* p  = (unsigned char*)ws;                        // 4 MB fp8
  float* rowsum     = (float*)(ws + (size_t)NROWS * DIM);        // 32 KB
  float* posp       = rowsum + NROWS;                            // 2 KB

  normalize_pos_kernel<<<512, 256, 0, stream>>>(zi, zj, p, rowsum, posp);
  simexp_kernel<<<SBLK, 256, 0, stream>>>(p, rowsum);
  finalize_kernel<<<1, 256, 0, stream>>>(rowsum, posp, out);
}

// Round 13
// 54.515 us; speedup vs baseline: 1.5938x; 1.5938x over previous
//
#include <hip/hip_runtime.h>
#include <hip/hip_bf16.h>
#include <stdint.h>

#define NB    4096
#define NROWS 8192
#define DIM   512
#define BM    128
#define TK    128                     // K per MX-fp8 MFMA tile
#define NKT   4                       // K-tiles per output tile
#define SBLK  768                     // simexp grid: 3 blocks/CU, persistent

typedef __attribute__((ext_vector_type(4))) float f32x4;
typedef __attribute__((ext_vector_type(4))) int   i32x4;
typedef __attribute__((ext_vector_type(8))) int   i32x8;

#define SCALE_E8M0 0x7B7B7B7Bu   // 2^-4 per 32-elem block, all blocks

// f32 -> OCP e4m3fn, RNE. Inputs |x| <= ~8 here (no sat needed).
__device__ __forceinline__ unsigned char f2e4m3(float x) {
  uint32_t u = __float_as_uint(x);
  uint32_t s = (u >> 24) & 0x80u;
  uint32_t e = (u >> 23) & 0xffu;
  if (e < 117u) return (unsigned char)s;          // < 2^-10 -> 0
  if (e >= 121u) {                                // normal fp8 range
    u += 0x7FFFFu + ((u >> 20) & 1u);             // RNE on mantissa bit 20
    e = (u >> 23) & 0xffu;
    uint32_t m = (u >> 20) & 7u;
    return (unsigned char)(s | ((e - 120u) << 3) | m);
  }
  float af = __uint_as_float(u & 0x7fffffffu);    // subnormal: step 2^-9
  int q = (int)(af * 512.0f + 0.5f);
  return (unsigned char)(q > 7 ? (s | 0x08u) : (s | (uint32_t)q));
}

__device__ __forceinline__ void gload_lds16(const void* g, void* l) {
  __builtin_amdgcn_global_load_lds(
      (const __attribute__((address_space(1))) void*)g,
      (__attribute__((address_space(3))) void*)l, 16, 0, 0);
}

__device__ __forceinline__ i32x8 ld_frag(const char* base, int o0, int o1) {
  i32x4 lo = *(const i32x4*)(base + o0);
  i32x4 hi = *(const i32x4*)(base + o1);
  i32x8 r = {lo[0], lo[1], lo[2], lo[3], hi[0], hi[1], hi[2], hi[3]};
  return r;
}

// ---- Kernel 1: normalize -> fp8 P (v*16), pos partials; 1024 blocks x1 ----
__global__ __launch_bounds__(256) void normalize_pos_kernel(
    const float* __restrict__ zi, const float* __restrict__ zj,
    unsigned char* __restrict__ p, float* __restrict__ rowsum,
    float* __restrict__ posp) {
  __shared__ float ws4[4];
  const int wave = threadIdx.x >> 6;
  const int lane = threadIdx.x & 63;
  const int i    = blockIdx.x * 4 + wave;          // 0..4095

  int gt = blockIdx.x * 256 + threadIdx.x;
  if (gt < NROWS) rowsum[gt] = 0.f;

  const float4* sa = (const float4*)(zi + (size_t)i * DIM);
  const float4* sb = (const float4*)(zj + (size_t)i * DIM);
  float4 a0 = sa[lane * 2], a1 = sa[lane * 2 + 1];
  float4 b0 = sb[lane * 2], b1 = sb[lane * 2 + 1];
  float va[8] = {a0.x, a0.y, a0.z, a0.w, a1.x, a1.y, a1.z, a1.w};
  float vb[8] = {b0.x, b0.y, b0.z, b0.w, b1.x, b1.y, b1.z, b1.w};
  float ssa = 0.f, ssb = 0.f;
#pragma unroll
  for (int j = 0; j < 8; ++j) { ssa += va[j] * va[j]; ssb += vb[j] * vb[j]; }
#pragma unroll
  for (int off = 32; off; off >>= 1) {
    ssa += __shfl_xor(ssa, off);
    ssb += __shfl_xor(ssb, off);
  }
  float inva = rsqrtf(ssa), invb = rsqrtf(ssb);
  union { unsigned char b[8]; uint2 v; } qa, qb;
  float d = 0.f;
#pragma unroll
  for (int j = 0; j < 8; ++j) {
    float na = va[j] * inva, nb = vb[j] * invb;
    qa.b[j] = f2e4m3(na * 16.0f);
    qb.b[j] = f2e4m3(nb * 16.0f);
    d += na * nb;
  }
  *(uint2*)(p + (size_t)i * DIM + lane * 8)        = qa.v;
  *(uint2*)(p + (size_t)(i + NB) * DIM + lane * 8) = qb.v;

#pragma unroll
  for (int off = 32; off; off >>= 1) d += __shfl_xor(d, off);
  if (lane == 0) ws4[wave] = d;
  __syncthreads();
  if (threadIdx.x == 0)
    posp[blockIdx.x] = 4.0f * (ws4[0] + ws4[1] + ws4[2] + ws4[3]);
}

// decode (xcd x, local slot l) -> tile (bi,bj); supertile partition (R3/R6):
__device__ __forceinline__ void decode_tile(int x, int l, int* pbi, int* pbj) {
  if (x < 6) {
    const int sqi[6] = {0, 0, 0, 1, 1, 2};
    const int sqj[6] = {1, 2, 3, 2, 3, 3};
    *pbi = sqi[x] * 16 + (l >> 4);
    *pbj = sqj[x] * 16 + (l & 15);
  } else {
    int s  = (x == 6) ? 0 : 2;
    int ll = l;
    if (ll >= 136) { ll -= 136; s += 1; }
    int i = 0;
    while ((i + 1) * (33 - (i + 1)) / 2 <= ll) ++i;
    int j = i + (ll - i * (33 - i) / 2);
    *pbi = s * 16 + i;
    *pbj = s * 16 + j;
  }
}

// ---- Kernel 2: symmetric fused S = 2*P*P^T (MX-fp8) -> exp -> row+col sums
// 768 persistent blocks, 3/CU (32 KB LDS single buffer; launch_bounds(256,3)
// -> VGPR cap ~170, NO spill — R12's regression was the (256,4) spill).
// Per-CU latency hiding = 3 independent phase-streams (m114 co-scheduling).
// Phase = R8's verified drain loop. Block b serves XCD b&7 with 2-3
// consecutive supertile tiles.
__global__ __launch_bounds__(256, 3) void simexp_kernel(
    const unsigned char* __restrict__ p, float* __restrict__ rowsum) {
  __shared__ __align__(16) unsigned char As[BM * TK];   // 16 KB
  __shared__ __align__(16) unsigned char Bs[BM * TK];   // 16 KB

  const int x  = blockIdx.x & 7;         // XCD
  const int lb = blockIdx.x >> 3;        // 0..95 local block
  int start, cnt;
  if (x < 6) {
    if (lb < 64) { start = lb * 3; cnt = 3; }            // 192
    else         { start = 192 + (lb - 64) * 2; cnt = 2; } // +64 = 256
  } else {
    if (lb < 80) { start = lb * 3; cnt = 3; }            // 240
    else         { start = 240 + (lb - 80) * 2; cnt = 2; } // +32 = 272
  }

  const int tid  = threadIdx.x;
  const int wave = tid >> 6;
  const int lane = tid & 63;
  const int wm   = wave >> 1;
  const int wn   = wave & 1;
  const int frow = lane & 15;
  const int kc   = lane >> 4;            // 0..3 : 32-elem k-block

  const int row8 = lane >> 3;            // 0..7
  const int gch  = (lane & 7) ^ row8;    // pre-swizzled 16B chunk

#define STAGE(bi_, bj_, t_)                                                   \
  {                                                                           \
    const unsigned char* pa_ = p + (size_t)((bi_)*BM) * DIM;                  \
    const unsigned char* pb_ = p + (size_t)((bj_)*BM) * DIM;                  \
    _Pragma("unroll")                                                         \
    for (int q = 0; q < 4; ++q) {                                             \
      int rbase = q * 32 + wave * 8;                                          \
      gload_lds16(pa_ + (size_t)(rbase + row8) * DIM + (t_)*TK + gch * 16,    \
                  (char*)As + rbase * 128);                                   \
      gload_lds16(pb_ + (size_t)(rbase + row8) * DIM + (t_)*TK + gch * 16,    \
                  (char*)Bs + rbase * 128);                                   \
    }                                                                         \
  }

  // ds_read byte offsets (verified R8): row*128 + ((kc*2+j)^(row&7))*16
  int offA[4][2], offB[4][2];
#pragma unroll
  for (int m = 0; m < 4; ++m) {
    int row = wm * 64 + m * 16 + frow;
#pragma unroll
    for (int j = 0; j < 2; ++j)
      offA[m][j] = row * 128 + ((kc * 2 + j) ^ (row & 7)) * 16;
  }
#pragma unroll
  for (int n = 0; n < 4; ++n) {
    int row = wn * 64 + n * 16 + frow;
#pragma unroll
    for (int j = 0; j < 2; ++j)
      offB[n][j] = row * 128 + ((kc * 2 + j) ^ (row & 7)) * 16;
  }

  const int r4 = lane >> 4;   // C/D: col = lane&15, row = (lane>>4)*4 + reg
  const int cl = lane & 15;

  for (int tt = 0; tt < cnt; ++tt) {
    int cbi, cbj;
    decode_tile(x, start + tt, &cbi, &cbj);
    const bool diag = (cbi == cbj);

    f32x4 acc[4][4] = {};

#pragma unroll
    for (int t = 0; t < NKT; ++t) {
      STAGE(cbi, cbj, t);
      __syncthreads();                       // drain + all waves' tile in
      {
        i32x8 af[4], bfr[4];
#pragma unroll
        for (int m = 0; m < 4; ++m)
          af[m] = ld_frag((const char*)As, offA[m][0], offA[m][1]);
#pragma unroll
        for (int n = 0; n < 4; ++n)
          bfr[n] = ld_frag((const char*)Bs, offB[n][0], offB[n][1]);
#pragma unroll
        for (int m = 0; m < 4; ++m)
#pragma unroll
          for (int n = 0; n < 4; ++n)
            acc[m][n] = __builtin_amdgcn_mfma_scale_f32_16x16x128_f8f6f4(
                af[m], bfr[n], acc[m][n], 0, 0, 0, SCALE_E8M0, 0, SCALE_E8M0);
      }
      __syncthreads();                       // reads done -> safe overwrite
    }

    // ---- epilogue for tile (cbi,cbj) (R8-verified) ----
    float rowpart[4][4];
    float colpart[4] = {0.f, 0.f, 0.f, 0.f};

    if (diag) {
#pragma unroll
      for (int m = 0; m < 4; ++m)
#pragma unroll
        for (int r = 0; r < 4; ++r) {
          int grow = cbi * BM + wm * 64 + m * 16 + r4 * 4 + r;
          float s = 0.f;
#pragma unroll
          for (int n = 0; n < 4; ++n) {
            int gcol = cbj * BM + wn * 64 + n * 16 + cl;
            float e  = __expf(2.0f * acc[m][n][r]);
            s += (grow == gcol) ? 0.f : e;
          }
          rowpart[m][r] = s;
        }
    } else {
#pragma unroll
      for (int m = 0; m < 4; ++m)
#pragma unroll
        for (int r = 0; r < 4; ++r) {
          float s = 0.f;
#pragma unroll
          for (int n = 0; n < 4; ++n) {
            float e = __expf(2.0f * acc[m][n][r]);
            s += e;
            colpart[n] += e;
          }
          rowpart[m][r] = s;
        }
    }

#pragma unroll
    for (int m = 0; m < 4; ++m)
#pragma unroll
      for (int r = 0; r < 4; ++r) {
        float s = rowpart[m][r];
        s += __shfl_xor(s, 1);
        s += __shfl_xor(s, 2);
        s += __shfl_xor(s, 4);
        s += __shfl_xor(s, 8);
        if (cl == 0) {
          int grow = cbi * BM + wm * 64 + m * 16 + r4 * 4 + r;
          atomicAdd(&rowsum[grow], s);
        }
      }

    if (!diag) {
#pragma unroll
      for (int n = 0; n < 4; ++n) {
        float c = colpart[n];
        c += __shfl_xor(c, 16);
        c += __shfl_xor(c, 32);
        if (r4 == 0) {
          int gcol = cbj * BM + wn * 64 + n * 16 + cl;
          atomicAdd(&rowsum[gcol], c);
        }
      }
    }
  }
}

// ---- Kernel 3a: partial finalize: 64 blocks -------------------------------
__global__ __launch_bounds__(256) void finalize1_kernel(
    const float* __restrict__ rowsum, const float* __restrict__ posp,
    float* __restrict__ part) {
  __shared__ float ws4[4];
  const int b   = blockIdx.x;
  const int tid = threadIdx.x;
  float v = 0.f;
  if (tid < 128)            v += logf(rowsum[b * 128 + tid]);
  else if (tid < 144)       v -= posp[b * 16 + (tid - 128)];
#pragma unroll
  for (int off = 32; off; off >>= 1) v += __shfl_xor(v, off);
  if ((tid & 63) == 0) ws4[tid >> 6] = v;
  __syncthreads();
  if (tid == 0) part[b] = ws4[0] + ws4[1] + ws4[2] + ws4[3];
}

// ---- Kernel 3b: final reduce ----------------------------------------------
__global__ __launch_bounds__(64) void finalize2_kernel(
    const float* __restrict__ part, float* __restrict__ out) {
  int tid = threadIdx.x;
  float v = part[tid];
#pragma unroll
  for (int off = 32; off; off >>= 1) v += __shfl_xor(v, off);
  if (tid == 0) out[0] = v / (float)NROWS;
}

extern "C" void kernel_launch(void* const* d_in, const int* in_sizes, int n_in,
                              void* d_out, int out_size, void* d_ws,
                              size_t ws_size, hipStream_t stream) {
  const float* zi = (const float*)d_in[0];
  const float* zj = (const float*)d_in[1];
  float* out      = (float*)d_out;

  char* ws          = (char*)d_ws;
  unsigned char* p  = (unsigned char*)ws;                        // 4 MB fp8
  float* rowsum     = (float*)(ws + (size_t)NROWS * DIM);        // 32 KB
  float* posp       = rowsum + NROWS;                            // 4 KB
  float* part       = posp + 1024;                               // 256 B

  normalize_pos_kernel<<<1024, 256, 0, stream>>>(zi, zj, p, rowsum, posp);
  simexp_kernel<<<SBLK, 256, 0, stream>>>(p, rowsum);
  finalize1_kernel<<<64, 256, 0, stream>>>(rowsum, posp, part);
  finalize2_kernel<<<1, 64, 0, stream>>>(part, out);
}

// Round 14
// 53.806 us; speedup vs baseline: 1.6148x; 1.0132x over previous
//
#include <hip/hip_runtime.h>
#include <hip/hip_bf16.h>
#include <stdint.h>

#define NB    4096
#define NROWS 8192
#define DIM   512
#define BM    128
#define TK    128                     // K per MX-fp8 MFMA tile
#define NKT   4                       // K-tiles per output tile
#define SBLK  768                     // simexp grid: 3 blocks/CU, persistent
#define NREP  8                       // rowsum replicas (one per blockIdx&7)

typedef __attribute__((ext_vector_type(4))) float f32x4;
typedef __attribute__((ext_vector_type(4))) int   i32x4;
typedef __attribute__((ext_vector_type(8))) int   i32x8;

#define SCALE_E8M0 0x7B7B7B7Bu   // 2^-4 per 32-elem block, all blocks

// f32 -> OCP e4m3fn, RNE. Inputs |x| <= ~8 here (no sat needed).
__device__ __forceinline__ unsigned char f2e4m3(float x) {
  uint32_t u = __float_as_uint(x);
  uint32_t s = (u >> 24) & 0x80u;
  uint32_t e = (u >> 23) & 0xffu;
  if (e < 117u) return (unsigned char)s;          // < 2^-10 -> 0
  if (e >= 121u) {                                // normal fp8 range
    u += 0x7FFFFu + ((u >> 20) & 1u);             // RNE on mantissa bit 20
    e = (u >> 23) & 0xffu;
    uint32_t m = (u >> 20) & 7u;
    return (unsigned char)(s | ((e - 120u) << 3) | m);
  }
  float af = __uint_as_float(u & 0x7fffffffu);    // subnormal: step 2^-9
  int q = (int)(af * 512.0f + 0.5f);
  return (unsigned char)(q > 7 ? (s | 0x08u) : (s | (uint32_t)q));
}

__device__ __forceinline__ void gload_lds16(const void* g, void* l) {
  __builtin_amdgcn_global_load_lds(
      (const __attribute__((address_space(1))) void*)g,
      (__attribute__((address_space(3))) void*)l, 16, 0, 0);
}

__device__ __forceinline__ i32x8 ld_frag(const char* base, int o0, int o1) {
  i32x4 lo = *(const i32x4*)(base + o0);
  i32x4 hi = *(const i32x4*)(base + o1);
  i32x8 r = {lo[0], lo[1], lo[2], lo[3], hi[0], hi[1], hi[2], hi[3]};
  return r;
}

// ---- Kernel 1: normalize -> fp8 P (v*16), pos partials; zero rowsum x8 ----
__global__ __launch_bounds__(256) void normalize_pos_kernel(
    const float* __restrict__ zi, const float* __restrict__ zj,
    unsigned char* __restrict__ p, float* __restrict__ rowsum,
    float* __restrict__ posp) {
  __shared__ float ws4[4];
  const int wave = threadIdx.x >> 6;
  const int lane = threadIdx.x & 63;
  const int i    = blockIdx.x * 4 + wave;          // 0..4095

  int gt = blockIdx.x * 256 + threadIdx.x;
  if (gt < NREP * NROWS) rowsum[gt] = 0.f;         // 65536 floats

  const float4* sa = (const float4*)(zi + (size_t)i * DIM);
  const float4* sb = (const float4*)(zj + (size_t)i * DIM);
  float4 a0 = sa[lane * 2], a1 = sa[lane * 2 + 1];
  float4 b0 = sb[lane * 2], b1 = sb[lane * 2 + 1];
  float va[8] = {a0.x, a0.y, a0.z, a0.w, a1.x, a1.y, a1.z, a1.w};
  float vb[8] = {b0.x, b0.y, b0.z, b0.w, b1.x, b1.y, b1.z, b1.w};
  float ssa = 0.f, ssb = 0.f;
#pragma unroll
  for (int j = 0; j < 8; ++j) { ssa += va[j] * va[j]; ssb += vb[j] * vb[j]; }
#pragma unroll
  for (int off = 32; off; off >>= 1) {
    ssa += __shfl_xor(ssa, off);
    ssb += __shfl_xor(ssb, off);
  }
  float inva = rsqrtf(ssa), invb = rsqrtf(ssb);
  union { unsigned char b[8]; uint2 v; } qa, qb;
  float d = 0.f;
#pragma unroll
  for (int j = 0; j < 8; ++j) {
    float na = va[j] * inva, nb = vb[j] * invb;
    qa.b[j] = f2e4m3(na * 16.0f);
    qb.b[j] = f2e4m3(nb * 16.0f);
    d += na * nb;
  }
  *(uint2*)(p + (size_t)i * DIM + lane * 8)        = qa.v;
  *(uint2*)(p + (size_t)(i + NB) * DIM + lane * 8) = qb.v;

#pragma unroll
  for (int off = 32; off; off >>= 1) d += __shfl_xor(d, off);
  if (lane == 0) ws4[wave] = d;
  __syncthreads();
  if (threadIdx.x == 0)
    posp[blockIdx.x] = 4.0f * (ws4[0] + ws4[1] + ws4[2] + ws4[3]);
}

// decode (xcd x, local slot l) -> tile (bi,bj); supertile partition (R3/R6):
__device__ __forceinline__ void decode_tile(int x, int l, int* pbi, int* pbj) {
  if (x < 6) {
    const int sqi[6] = {0, 0, 0, 1, 1, 2};
    const int sqj[6] = {1, 2, 3, 2, 3, 3};
    *pbi = sqi[x] * 16 + (l >> 4);
    *pbj = sqj[x] * 16 + (l & 15);
  } else {
    int s  = (x == 6) ? 0 : 2;
    int ll = l;
    if (ll >= 136) { ll -= 136; s += 1; }
    int i = 0;
    while ((i + 1) * (33 - (i + 1)) / 2 <= ll) ++i;
    int j = i + (ll - i * (33 - i) / 2);
    *pbi = s * 16 + i;
    *pbj = s * 16 + j;
  }
}

// ---- Kernel 2: symmetric fused S = 2*P*P^T (MX-fp8) -> exp -> row+col sums
// R13 structure (768 persistent blocks, 3/CU, R8 drain phase). ONE change:
// rowsum is replicated x8, replica = blockIdx&7 (same index as supertile
// owner) -> 8x less atomic contention, replica lines stay XCD-local.
__global__ __launch_bounds__(256, 3) void simexp_kernel(
    const unsigned char* __restrict__ p, float* __restrict__ rowsum) {
  __shared__ __align__(16) unsigned char As[BM * TK];   // 16 KB
  __shared__ __align__(16) unsigned char Bs[BM * TK];   // 16 KB

  const int x  = blockIdx.x & 7;         // XCD / replica
  const int lb = blockIdx.x >> 3;        // 0..95 local block
  int start, cnt;
  if (x < 6) {
    if (lb < 64) { start = lb * 3; cnt = 3; }              // 192
    else         { start = 192 + (lb - 64) * 2; cnt = 2; } // +64 = 256
  } else {
    if (lb < 80) { start = lb * 3; cnt = 3; }              // 240
    else         { start = 240 + (lb - 80) * 2; cnt = 2; } // +32 = 272
  }

  float* __restrict__ rs = rowsum + (size_t)x * NROWS;   // my replica

  const int tid  = threadIdx.x;
  const int wave = tid >> 6;
  const int lane = tid & 63;
  const int wm   = wave >> 1;
  const int wn   = wave & 1;
  const int frow = lane & 15;
  const int kc   = lane >> 4;            // 0..3 : 32-elem k-block

  const int row8 = lane >> 3;            // 0..7
  const int gch  = (lane & 7) ^ row8;    // pre-swizzled 16B chunk

#define STAGE(bi_, bj_, t_)                                                   \
  {                                                                           \
    const unsigned char* pa_ = p + (size_t)((bi_)*BM) * DIM;                  \
    const unsigned char* pb_ = p + (size_t)((bj_)*BM) * DIM;                  \
    _Pragma("unroll")                                                         \
    for (int q = 0; q < 4; ++q) {                                             \
      int rbase = q * 32 + wave * 8;                                          \
      gload_lds16(pa_ + (size_t)(rbase + row8) * DIM + (t_)*TK + gch * 16,    \
                  (char*)As + rbase * 128);                                   \
      gload_lds16(pb_ + (size_t)(rbase + row8) * DIM + (t_)*TK + gch * 16,    \
                  (char*)Bs + rbase * 128);                                   \
    }                                                                         \
  }

  // ds_read byte offsets (verified R8): row*128 + ((kc*2+j)^(row&7))*16
  int offA[4][2], offB[4][2];
#pragma unroll
  for (int m = 0; m < 4; ++m) {
    int row = wm * 64 + m * 16 + frow;
#pragma unroll
    for (int j = 0; j < 2; ++j)
      offA[m][j] = row * 128 + ((kc * 2 + j) ^ (row & 7)) * 16;
  }
#pragma unroll
  for (int n = 0; n < 4; ++n) {
    int row = wn * 64 + n * 16 + frow;
#pragma unroll
    for (int j = 0; j < 2; ++j)
      offB[n][j] = row * 128 + ((kc * 2 + j) ^ (row & 7)) * 16;
  }

  const int r4 = lane >> 4;   // C/D: col = lane&15, row = (lane>>4)*4 + reg
  const int cl = lane & 15;

  for (int tt = 0; tt < cnt; ++tt) {
    int cbi, cbj;
    decode_tile(x, start + tt, &cbi, &cbj);
    const bool diag = (cbi == cbj);

    f32x4 acc[4][4] = {};

#pragma unroll
    for (int t = 0; t < NKT; ++t) {
      STAGE(cbi, cbj, t);
      __syncthreads();                       // drain + all waves' tile in
      {
        i32x8 af[4], bfr[4];
#pragma unroll
        for (int m = 0; m < 4; ++m)
          af[m] = ld_frag((const char*)As, offA[m][0], offA[m][1]);
#pragma unroll
        for (int n = 0; n < 4; ++n)
          bfr[n] = ld_frag((const char*)Bs, offB[n][0], offB[n][1]);
#pragma unroll
        for (int m = 0; m < 4; ++m)
#pragma unroll
          for (int n = 0; n < 4; ++n)
            acc[m][n] = __builtin_amdgcn_mfma_scale_f32_16x16x128_f8f6f4(
                af[m], bfr[n], acc[m][n], 0, 0, 0, SCALE_E8M0, 0, SCALE_E8M0);
      }
      __syncthreads();                       // reads done -> safe overwrite
    }

    // ---- epilogue for tile (cbi,cbj) (R8-verified; atomics -> replica) ----
    float rowpart[4][4];
    float colpart[4] = {0.f, 0.f, 0.f, 0.f};

    if (diag) {
#pragma unroll
      for (int m = 0; m < 4; ++m)
#pragma unroll
        for (int r = 0; r < 4; ++r) {
          int grow = cbi * BM + wm * 64 + m * 16 + r4 * 4 + r;
          float s = 0.f;
#pragma unroll
          for (int n = 0; n < 4; ++n) {
            int gcol = cbj * BM + wn * 64 + n * 16 + cl;
            float e  = __expf(2.0f * acc[m][n][r]);
            s += (grow == gcol) ? 0.f : e;
          }
          rowpart[m][r] = s;
        }
    } else {
#pragma unroll
      for (int m = 0; m < 4; ++m)
#pragma unroll
        for (int r = 0; r < 4; ++r) {
          float s = 0.f;
#pragma unroll
          for (int n = 0; n < 4; ++n) {
            float e = __expf(2.0f * acc[m][n][r]);
            s += e;
            colpart[n] += e;
          }
          rowpart[m][r] = s;
        }
    }

#pragma unroll
    for (int m = 0; m < 4; ++m)
#pragma unroll
      for (int r = 0; r < 4; ++r) {
        float s = rowpart[m][r];
        s += __shfl_xor(s, 1);
        s += __shfl_xor(s, 2);
        s += __shfl_xor(s, 4);
        s += __shfl_xor(s, 8);
        if (cl == 0) {
          int grow = cbi * BM + wm * 64 + m * 16 + r4 * 4 + r;
          atomicAdd(&rs[grow], s);
        }
      }

    if (!diag) {
#pragma unroll
      for (int n = 0; n < 4; ++n) {
        float c = colpart[n];
        c += __shfl_xor(c, 16);
        c += __shfl_xor(c, 32);
        if (r4 == 0) {
          int gcol = cbj * BM + wn * 64 + n * 16 + cl;
          atomicAdd(&rs[gcol], c);
        }
      }
    }
  }
}

// ---- Kernel 3a: partial finalize: 64 blocks (sum replicas + log) ----------
__global__ __launch_bounds__(256) void finalize1_kernel(
    const float* __restrict__ rowsum, const float* __restrict__ posp,
    float* __restrict__ part) {
  __shared__ float ws4[4];
  const int b   = blockIdx.x;
  const int tid = threadIdx.x;
  float v = 0.f;
  if (tid < 128) {
    int row = b * 128 + tid;
    float s = 0.f;
#pragma unroll
    for (int r = 0; r < NREP; ++r) s += rowsum[r * NROWS + row];
    v += logf(s);
  } else if (tid < 144) {
    v -= posp[b * 16 + (tid - 128)];
  }
#pragma unroll
  for (int off = 32; off; off >>= 1) v += __shfl_xor(v, off);
  if ((tid & 63) == 0) ws4[tid >> 6] = v;
  __syncthreads();
  if (tid == 0) part[b] = ws4[0] + ws4[1] + ws4[2] + ws4[3];
}

// ---- Kernel 3b: final reduce ----------------------------------------------
__global__ __launch_bounds__(64) void finalize2_kernel(
    const float* __restrict__ part, float* __restrict__ out) {
  int tid = threadIdx.x;
  float v = part[tid];
#pragma unroll
  for (int off = 32; off; off >>= 1) v += __shfl_xor(v, off);
  if (tid == 0) out[0] = v / (float)NROWS;
}

extern "C" void kernel_launch(void* const* d_in, const int* in_sizes, int n_in,
                              void* d_out, int out_size, void* d_ws,
                              size_t ws_size, hipStream_t stream) {
  const float* zi = (const float*)d_in[0];
  const float* zj = (const float*)d_in[1];
  float* out      = (float*)d_out;

  char* ws          = (char*)d_ws;
  unsigned char* p  = (unsigned char*)ws;                        // 4 MB fp8
  float* rowsum     = (float*)(ws + (size_t)NROWS * DIM);        // 256 KB (x8)
  float* posp       = rowsum + NREP * NROWS;                     // 4 KB
  float* part       = posp + 1024;                               // 256 B

  normalize_pos_kernel<<<1024, 256, 0, stream>>>(zi, zj, p, rowsum, posp);
  simexp_kernel<<<SBLK, 256, 0, stream>>>(p, rowsum);
  finalize1_kernel<<<64, 256, 0, stream>>>(rowsum, posp, part);
  finalize2_kernel<<<1, 64, 0, stream>>>(part, out);
}

// Round 16
// 42.676 us; speedup vs baseline: 2.0359x; 1.2608x over previous
//
#include <hip/hip_runtime.h>
#include <hip/hip_bf16.h>
#include <stdint.h>

#define NB    4096
#define NROWS 8192
#define DIM   512
#define BM    128
#define ROWB  256                     // bytes per fp4 row (512 elems)
#define SBLK  512                     // simexp: 2 blocks/CU, persistent
#define NREP  8                       // rowsum replicas

typedef __attribute__((ext_vector_type(4))) float f32x4;
typedef __attribute__((ext_vector_type(4))) int   i32x4;
typedef __attribute__((ext_vector_type(8))) int   i32x8;

#define SCALE_E8M0 0x7A7A7A7Au   // 2^-5 per 32-elem block, all blocks

// f32 (pre-scaled by 32) -> OCP e2m1 nibble, RNE-ish, clamp to 6.
__device__ __forceinline__ uint32_t f2e2m1(float x) {
  uint32_t s = (__float_as_uint(x) >> 28) & 0x8u;
  float a = fabsf(x);
  uint32_t m =
      (a <= 0.25f) ? 0u :
      (a <  0.75f) ? 1u :
      (a <= 1.25f) ? 2u :
      (a <  1.75f) ? 3u :
      (a <= 2.50f) ? 4u :
      (a <  3.50f) ? 5u :
      (a <= 5.00f) ? 6u : 7u;
  return s | m;
}

__device__ __forceinline__ void gload_lds16(const void* g, void* l) {
  __builtin_amdgcn_global_load_lds(
      (const __attribute__((address_space(1))) void*)g,
      (__attribute__((address_space(3))) void*)l, 16, 0, 0);
}

__device__ __forceinline__ i32x8 pad8(i32x4 v) {
  i32x8 r = {v[0], v[1], v[2], v[3], 0, 0, 0, 0};
  return r;
}

// ---- Kernel 1: normalize -> fp4 P (v*32, e2m1), pos partials, zero rowsum -
__global__ __launch_bounds__(256) void normalize_pos_kernel(
    const float* __restrict__ zi, const float* __restrict__ zj,
    unsigned char* __restrict__ p, float* __restrict__ rowsum,
    float* __restrict__ posp) {
  __shared__ float ws4[4];
  const int wave = threadIdx.x >> 6;
  const int lane = threadIdx.x & 63;
  const int i    = blockIdx.x * 4 + wave;          // 0..4095

  int gt = blockIdx.x * 256 + threadIdx.x;
  if (gt < NREP * NROWS) rowsum[gt] = 0.f;

  const float4* sa = (const float4*)(zi + (size_t)i * DIM);
  const float4* sb = (const float4*)(zj + (size_t)i * DIM);
  float4 a0 = sa[lane * 2], a1 = sa[lane * 2 + 1];
  float4 b0 = sb[lane * 2], b1 = sb[lane * 2 + 1];
  float va[8] = {a0.x, a0.y, a0.z, a0.w, a1.x, a1.y, a1.z, a1.w};
  float vb[8] = {b0.x, b0.y, b0.z, b0.w, b1.x, b1.y, b1.z, b1.w};
  float ssa = 0.f, ssb = 0.f;
#pragma unroll
  for (int j = 0; j < 8; ++j) { ssa += va[j] * va[j]; ssb += vb[j] * vb[j]; }
#pragma unroll
  for (int off = 32; off; off >>= 1) {
    ssa += __shfl_xor(ssa, off);
    ssb += __shfl_xor(ssb, off);
  }
  float inva = rsqrtf(ssa), invb = rsqrtf(ssb);

  uint32_t pa = 0, pb = 0;
  float d = 0.f;
#pragma unroll
  for (int j = 0; j < 8; ++j) {
    float na = va[j] * inva, nb = vb[j] * invb;
    pa |= f2e2m1(na * 32.0f) << (4 * j);
    pb |= f2e2m1(nb * 32.0f) << (4 * j);
    d += na * nb;
  }
  *(uint32_t*)(p + (size_t)i * ROWB + lane * 4)        = pa;
  *(uint32_t*)(p + (size_t)(i + NB) * ROWB + lane * 4) = pb;

#pragma unroll
  for (int off = 32; off; off >>= 1) d += __shfl_xor(d, off);
  if (lane == 0) ws4[wave] = d;
  __syncthreads();
  if (threadIdx.x == 0)
    posp[blockIdx.x] = 4.0f * (ws4[0] + ws4[1] + ws4[2] + ws4[3]);
}

// decode (xcd x, local slot l) -> tile (bi,bj); supertile partition (R3+):
__device__ __forceinline__ void decode_tile(int x, int l, int* pbi, int* pbj) {
  if (x < 6) {
    const int sqi[6] = {0, 0, 0, 1, 1, 2};
    const int sqj[6] = {1, 2, 3, 2, 3, 3};
    *pbi = sqi[x] * 16 + (l >> 4);
    *pbj = sqj[x] * 16 + (l & 15);
  } else {
    int s  = (x == 6) ? 0 : 2;
    int ll = l;
    if (ll >= 136) { ll -= 136; s += 1; }
    int i = 0;
    while ((i + 1) * (33 - (i + 1)) / 2 <= ll) ++i;
    int j = i + (ll - i * (33 - i) / 2);
    *pbi = s * 16 + i;
    *pbj = s * 16 + j;
  }
}

// ---- Kernel 2: symmetric fused S = 2*P*P^T (MX-fp4 K=128) -----------------
// 512 persistent blocks (2/CU). Whole-K panels in LDS: A[128][256B] +
// B[128][256B] = 64 KB. Per tile: stage B (A only when bi changes), ONE
// drain, 64 MFMA/wave uninterrupted, epilogue, one trailing barrier.
// LDS[r][ch16] = G[r][ch ^ (r&15)] (pre-swizzled global source, linear dest).
__global__ __launch_bounds__(256, 2) void simexp_kernel(
    const unsigned char* __restrict__ p, float* __restrict__ rowsum) {
  __shared__ __align__(16) unsigned char As[BM * ROWB];   // 32 KB
  __shared__ __align__(16) unsigned char Bs[BM * ROWB];   // 32 KB

  const int x  = blockIdx.x & 7;         // XCD / replica
  const int lb = blockIdx.x >> 3;        // 0..63 local block
  int start, cnt;
  if (x < 6) { start = lb * 4; cnt = 4; }                       // 256 tiles
  else if (lb < 48) { start = lb * 4; cnt = 4; }                // 272 tiles
  else { start = 192 + (lb - 48) * 5; cnt = 5; }

  float* __restrict__ rs = rowsum + (size_t)x * NROWS;

  const int tid  = threadIdx.x;
  const int wave = tid >> 6;
  const int lane = tid & 63;
  const int wm   = wave >> 1;
  const int wn   = wave & 1;
  const int frow = lane & 15;
  const int kc   = lane >> 4;            // 0..3 : 32-elem k-block

  const int row4 = lane >> 4;            // staging: 0..3 row within 4-row rib
  const int ch   = lane & 15;            // staging: 16B chunk

  // stage one whole 128x512 fp4 panel (32 KB): 8 ribs of 4 rows per wave
#define STAGE_PANEL(dst_, rowbase_)                                           \
  {                                                                           \
    _Pragma("unroll")                                                         \
    for (int q = 0; q < 8; ++q) {                                             \
      int rbase = wave * 32 + q * 4;                                          \
      int gch   = ch ^ ((rbase + row4) & 15);                                 \
      gload_lds16(p + (size_t)((rowbase_) + rbase + row4) * ROWB + gch * 16,  \
                  (char*)(dst_) + rbase * ROWB);                              \
    }                                                                         \
  }

  const int r4 = lane >> 4;   // C/D: col = lane&15, row = (lane>>4)*4 + reg
  const int cl = lane & 15;

  int pbi = -1;
  for (int tt = 0; tt < cnt; ++tt) {
    int cbi, cbj;
    decode_tile(x, start + tt, &cbi, &cbj);
    const bool diag = (cbi == cbj);

    if (cbi != pbi) STAGE_PANEL(As, cbi * BM);
    STAGE_PANEL(Bs, cbj * BM);
    pbi = cbi;
    __syncthreads();                     // drain (vmcnt0) + all waves in

    f32x4 acc[4][4] = {};
#pragma unroll
    for (int t = 0; t < 4; ++t) {
      const int coft = (((t * 4 + kc) ^ frow) * 16);
      i32x8 af[4], bfr[4];
#pragma unroll
      for (int m = 0; m < 4; ++m)
        af[m] = pad8(*(const i32x4*)(
            As + (wm * 64 + m * 16 + frow) * ROWB + coft));
#pragma unroll
      for (int n = 0; n < 4; ++n)
        bfr[n] = pad8(*(const i32x4*)(
            Bs + (wn * 64 + n * 16 + frow) * ROWB + coft));
#pragma unroll
      for (int m = 0; m < 4; ++m)
#pragma unroll
        for (int n = 0; n < 4; ++n)
          acc[m][n] = __builtin_amdgcn_mfma_scale_f32_16x16x128_f8f6f4(
              af[m], bfr[n], acc[m][n], 4 /*fp4*/, 4 /*fp4*/,
              0, SCALE_E8M0, 0, SCALE_E8M0);
    }

    // ---- epilogue (R8-verified): exp(2s) -> row + col replica sums --------
    float rowpart[4][4];
    float colpart[4] = {0.f, 0.f, 0.f, 0.f};

    if (diag) {
#pragma unroll
      for (int m = 0; m < 4; ++m)
#pragma unroll
        for (int r = 0; r < 4; ++r) {
          int grow = cbi * BM + wm * 64 + m * 16 + r4 * 4 + r;
          float s = 0.f;
#pragma unroll
          for (int n = 0; n < 4; ++n) {
            int gcol = cbj * BM + wn * 64 + n * 16 + cl;
            float e  = __expf(2.0f * acc[m][n][r]);
            s += (grow == gcol) ? 0.f : e;
          }
          rowpart[m][r] = s;
        }
    } else {
#pragma unroll
      for (int m = 0; m < 4; ++m)
#pragma unroll
        for (int r = 0; r < 4; ++r) {
          float s = 0.f;
#pragma unroll
          for (int n = 0; n < 4; ++n) {
            float e = __expf(2.0f * acc[m][n][r]);
            s += e;
            colpart[n] += e;
          }
          rowpart[m][r] = s;
        }
    }

#pragma unroll
    for (int m = 0; m < 4; ++m)
#pragma unroll
      for (int r = 0; r < 4; ++r) {
        float s = rowpart[m][r];
        s += __shfl_xor(s, 1);
        s += __shfl_xor(s, 2);
        s += __shfl_xor(s, 4);
        s += __shfl_xor(s, 8);
        if (cl == 0) {
          int grow = cbi * BM + wm * 64 + m * 16 + r4 * 4 + r;
          atomicAdd(&rs[grow], s);
        }
      }

    if (!diag) {
#pragma unroll
      for (int n = 0; n < 4; ++n) {
        float c = colpart[n];
        c += __shfl_xor(c, 16);
        c += __shfl_xor(c, 32);
        if (r4 == 0) {
          int gcol = cbj * BM + wn * 64 + n * 16 + cl;
          atomicAdd(&rs[gcol], c);
        }
      }
    }

    __syncthreads();                     // reads done -> next stage may ovw
  }
}

// ---- Kernel 3a: partial finalize: 64 blocks (sum replicas + log) ----------
__global__ __launch_bounds__(256) void finalize1_kernel(
    const float* __restrict__ rowsum, const float* __restrict__ posp,
    float* __restrict__ part) {
  __shared__ float ws4[4];
  const int b   = blockIdx.x;
  const int tid = threadIdx.x;
  float v = 0.f;
  if (tid < 128) {
    int row = b * 128 + tid;
    float s = 0.f;
#pragma unroll
    for (int r = 0; r < NREP; ++r) s += rowsum[r * NROWS + row];
    v += logf(s);
  } else if (tid < 144) {
    v -= posp[b * 16 + (tid - 128)];
  }
#pragma unroll
  for (int off = 32; off; off >>= 1) v += __shfl_xor(v, off);
  if ((tid & 63) == 0) ws4[tid >> 6] = v;
  __syncthreads();
  if (tid == 0) part[b] = ws4[0] + ws4[1] + ws4[2] + ws4[3];
}

// ---- Kernel 3b: final reduce ----------------------------------------------
__global__ __launch_bounds__(64) void finalize2_kernel(
    const float* __restrict__ part, float* __restrict__ out) {
  int tid = threadIdx.x;
  float v = part[tid];
#pragma unroll
  for (int off = 32; off; off >>= 1) v += __shfl_xor(v, off);
  if (tid == 0) out[0] = v / (float)NROWS;
}

extern "C" void kernel_launch(void* const* d_in, const int* in_sizes, int n_in,
                              void* d_out, int out_size, void* d_ws,
                              size_t ws_size, hipStream_t stream) {
  const float* zi = (const float*)d_in[0];
  const float* zj = (const float*)d_in[1];
  float* out      = (float*)d_out;

  char* ws          = (char*)d_ws;
  unsigned char* p  = (unsigned char*)ws;                        // 2 MB fp4
  float* rowsum     = (float*)(ws + (size_t)NROWS * ROWB);       // 256 KB (x8)
  float* posp       = rowsum + NREP * NROWS;                     // 4 KB
  float* part       = posp + 1024;                               // 256 B

  normalize_pos_kernel<<<1024, 256, 0, stream>>>(zi, zj, p, rowsum, posp);
  simexp_kernel<<<SBLK, 256, 0, stream>>>(p, rowsum);
  finalize1_kernel<<<64, 256, 0, stream>>>(rowsum, posp, part);
  finalize2_kernel<<<1, 64, 0, stream>>>(part, out);
}